// Round 2
// baseline (2161.694 us; speedup 1.0000x reference)
//
#include <hip/hip_runtime.h>
#include <math.h>

#define NFEAT 512
#define NHID  256
#define NCLASS 40
#define SCAN_CHUNK 1024

// ---------------- degree / norm ----------------

__global__ void zero_cnt_k(int* cnt, int n) {
    int i = blockIdx.x * 256 + threadIdx.x;
    if (i < n) cnt[i] = 0;
}

// NOTE: harness stages integer inputs as int32 (not the reference's int64).
__global__ void hist_k(const int* __restrict__ ei, int* cnt, int E) {
    int e = blockIdx.x * 256 + threadIdx.x;
    if (e < E) {
        int d = ei[(size_t)E + e];
        atomicAdd(&cnt[d], 1);
    }
}

__global__ void dis_k(const int* __restrict__ cnt, float* dis, int n) {
    int i = blockIdx.x * 256 + threadIdx.x;
    if (i < n) dis[i] = rsqrtf((float)cnt[i] + 1.0f);  // +1 self loop; deg>=1 always
}

// ---------------- exclusive scan (3 kernels) ----------------

__global__ void scanA_k(const int* __restrict__ cnt, int* bsum, int n) {
    __shared__ int sd[256];
    int t = threadIdx.x;
    int base = blockIdx.x * SCAN_CHUNK + t * 4;
    int s = 0;
#pragma unroll
    for (int r = 0; r < 4; ++r) {
        int i = base + r;
        if (i < n) s += cnt[i];
    }
    sd[t] = s;
    __syncthreads();
    for (int off = 128; off > 0; off >>= 1) {
        if (t < off) sd[t] += sd[t + off];
        __syncthreads();
    }
    if (t == 0) bsum[blockIdx.x] = sd[0];
}

__global__ void scanB_k(const int* __restrict__ bsum, int* boff, int nb) {
    __shared__ int sd[256];
    int t = threadIdx.x;
    int v = (t < nb) ? bsum[t] : 0;
    sd[t] = v;
    __syncthreads();
    for (int off = 1; off < 256; off <<= 1) {
        int add = (t >= off) ? sd[t - off] : 0;
        __syncthreads();
        sd[t] += add;
        __syncthreads();
    }
    if (t < nb) boff[t] = sd[t] - v;  // exclusive
}

__global__ void scanC_k(const int* __restrict__ cnt, const int* __restrict__ boff,
                        int* offs, int* cursor, int n, int E) {
    __shared__ int sd[256];
    int t = threadIdx.x, b = blockIdx.x;
    int base = b * SCAN_CHUNK + t * 4;
    int v[4];
    int s = 0;
#pragma unroll
    for (int r = 0; r < 4; ++r) {
        int i = base + r;
        v[r] = (i < n) ? cnt[i] : 0;
        s += v[r];
    }
    sd[t] = s;
    __syncthreads();
    for (int off = 1; off < 256; off <<= 1) {
        int add = (t >= off) ? sd[t - off] : 0;
        __syncthreads();
        sd[t] += add;
        __syncthreads();
    }
    int pos = boff[b] + (sd[t] - s);  // exclusive within block + block offset
#pragma unroll
    for (int r = 0; r < 4; ++r) {
        int i = base + r;
        if (i < n) { offs[i] = pos; cursor[i] = pos; }
        pos += v[r];
    }
    if (b == 0 && t == 0) offs[n] = E;
}

__global__ void fill_k(const int* __restrict__ ei, const float* __restrict__ dis,
                       int* cursor, int* csr_src, float* csr_w, int E) {
    int e = blockIdx.x * 256 + threadIdx.x;
    if (e < E) {
        int s = ei[e];
        int d = ei[(size_t)E + e];
        int pos = atomicAdd(&cursor[d], 1);
        csr_src[pos] = s;
        csr_w[pos] = dis[s] * dis[d];
    }
}

// ---------------- GEMM1: H = X(Mx512) * W(512x256), fp32 tiled ----------------

#define BM 64
#define BN 64
#define BK 32

__global__ __launch_bounds__(256) void gemm1_k(const float* __restrict__ X,
                                               const float* __restrict__ W,
                                               float* __restrict__ H, int M) {
    __shared__ float xs[BK][BM + 4];  // k-major, pad 4 keeps float4 alignment
    __shared__ float ws[BK][BN];
    int t = threadIdx.x;
    int m0 = blockIdx.x * BM;
    int j0 = blockIdx.y * BN;
    int tm = (t >> 4) * 4;   // 0..60
    int tj = (t & 15) * 4;   // 0..60
    float acc[4][4] = {};

    for (int k0 = 0; k0 < NFEAT; k0 += BK) {
#pragma unroll
        for (int r = 0; r < 8; ++r) {          // stage X tile: 64 x 32
            int e = t + 256 * r;
            int m = e >> 5, kk = e & 31;
            int gi = m0 + m;
            xs[kk][m] = (gi < M) ? X[(size_t)gi * NFEAT + k0 + kk] : 0.0f;
        }
#pragma unroll
        for (int r = 0; r < 8; ++r) {          // stage W tile: 32 x 64
            int e = t + 256 * r;
            int kk = e >> 6, jj = e & 63;
            ws[kk][jj] = W[(size_t)(k0 + kk) * NHID + j0 + jj];
        }
        __syncthreads();
#pragma unroll
        for (int kk = 0; kk < BK; ++kk) {
            float4 xv = *reinterpret_cast<const float4*>(&xs[kk][tm]);
            float4 wv = *reinterpret_cast<const float4*>(&ws[kk][tj]);
            acc[0][0] += xv.x * wv.x; acc[0][1] += xv.x * wv.y; acc[0][2] += xv.x * wv.z; acc[0][3] += xv.x * wv.w;
            acc[1][0] += xv.y * wv.x; acc[1][1] += xv.y * wv.y; acc[1][2] += xv.y * wv.z; acc[1][3] += xv.y * wv.w;
            acc[2][0] += xv.z * wv.x; acc[2][1] += xv.z * wv.y; acc[2][2] += xv.z * wv.z; acc[2][3] += xv.z * wv.w;
            acc[3][0] += xv.w * wv.x; acc[3][1] += xv.w * wv.y; acc[3][2] += xv.w * wv.z; acc[3][3] += xv.w * wv.w;
        }
        __syncthreads();
    }
#pragma unroll
    for (int a = 0; a < 4; ++a) {
        int gi = m0 + tm + a;
        if (gi < M) {
            float4 o = make_float4(acc[a][0], acc[a][1], acc[a][2], acc[a][3]);
            *reinterpret_cast<float4*>(&H[(size_t)gi * NHID + j0 + tj]) = o;
        }
    }
}

// ---------------- aggregation layer 1 (256 feat) + bias + relu ----------------

__global__ __launch_bounds__(256) void agg1_k(const float* __restrict__ H,
                                              const int* __restrict__ offs,
                                              const int* __restrict__ csr_src,
                                              const float* __restrict__ csr_w,
                                              const float* __restrict__ dis,
                                              const float* __restrict__ b1,
                                              float* __restrict__ out, int n) {
    int i = blockIdx.x;
    int j = threadIdx.x;
    int beg = offs[i], end = offs[i + 1];
    float acc = 0.0f;
    for (int e = beg; e < end; ++e) {
        int s = csr_src[e];
        float w = csr_w[e];
        acc += w * H[(size_t)s * NHID + j];
    }
    float di = dis[i];
    acc += di * di * H[(size_t)i * NHID + j];  // self loop
    acc += b1[j];
    out[(size_t)i * NHID + j] = fmaxf(acc, 0.0f);
}

// ---------------- GEMM2: H2 = A(Mx256) * W2(256x40), elementwise ----------------

__global__ __launch_bounds__(256) void gemm2_k(const float* __restrict__ A,
                                               const float* __restrict__ W,
                                               float* __restrict__ H2, int M) {
    int idx = blockIdx.x * 256 + threadIdx.x;
    if (idx >= M * NCLASS) return;
    int i = idx / NCLASS;
    int j = idx - i * NCLASS;
    float acc = 0.0f;
    const float* arow = A + (size_t)i * NHID;
#pragma unroll 4
    for (int k = 0; k < NHID; ++k) acc += arow[k] * W[k * NCLASS + j];
    H2[idx] = acc;
}

// ---------------- aggregation layer 2 (40 feat) + bias ----------------

__global__ __launch_bounds__(256) void agg2_k(const float* __restrict__ H2,
                                              const int* __restrict__ offs,
                                              const int* __restrict__ csr_src,
                                              const float* __restrict__ csr_w,
                                              const float* __restrict__ dis,
                                              const float* __restrict__ b2,
                                              float* __restrict__ out, int n) {
    int i = blockIdx.x * 4 + (threadIdx.x >> 6);
    int j = threadIdx.x & 63;
    if (i >= n || j >= NCLASS) return;
    int beg = offs[i], end = offs[i + 1];
    float acc = 0.0f;
    for (int e = beg; e < end; ++e) {
        acc += csr_w[e] * H2[(size_t)csr_src[e] * NCLASS + j];
    }
    float di = dis[i];
    acc += di * di * H2[(size_t)i * NCLASS + j];
    acc += b2[j];
    out[(size_t)i * NCLASS + j] = acc;
}

// ---------------- log_softmax per row (one wave per node, in place) ----------------

__global__ __launch_bounds__(256) void lsm_k(float* __restrict__ out, int n) {
    int i = blockIdx.x * 4 + (threadIdx.x >> 6);
    int j = threadIdx.x & 63;
    if (i >= n) return;
    float v = (j < NCLASS) ? out[(size_t)i * NCLASS + j] : -INFINITY;
    float m = v;
#pragma unroll
    for (int off = 32; off > 0; off >>= 1) m = fmaxf(m, __shfl_xor(m, off, 64));
    float e = (j < NCLASS) ? expf(v - m) : 0.0f;
    float s = e;
#pragma unroll
    for (int off = 32; off > 0; off >>= 1) s += __shfl_xor(s, off, 64);
    if (j < NCLASS) out[(size_t)i * NCLASS + j] = v - m - logf(s);
}

// ---------------- launch ----------------

extern "C" void kernel_launch(void* const* d_in, const int* in_sizes, int n_in,
                              void* d_out, int out_size, void* d_ws, size_t ws_size,
                              hipStream_t stream) {
    const float* x  = (const float*)d_in[0];
    const float* W1 = (const float*)d_in[1];
    const float* b1 = (const float*)d_in[2];
    const float* W2 = (const float*)d_in[3];
    const float* b2 = (const float*)d_in[4];
    const int*   ei = (const int*)d_in[5];   // harness stages integers as int32

    const int N = in_sizes[0] / NFEAT;      // 100000
    const int E = in_sizes[5] / 2;          // 3200000

    // workspace layout (all 256B aligned)
    size_t off = 0;
    auto alloc = [&](size_t bytes) { size_t o = off; off += (bytes + 255) & ~(size_t)255; return o; };
    char* ws = (char*)d_ws;
    int*   cnt     = (int*)  (ws + alloc((size_t)N * 4));
    int*   offs    = (int*)  (ws + alloc((size_t)(N + 1) * 4));
    int*   cursor  = (int*)  (ws + alloc((size_t)N * 4));
    float* dis     = (float*)(ws + alloc((size_t)N * 4));
    int*   bsum    = (int*)  (ws + alloc(256 * 4));
    int*   boff    = (int*)  (ws + alloc(256 * 4));
    int*   csr_src = (int*)  (ws + alloc((size_t)E * 4));
    float* csr_w   = (float*)(ws + alloc((size_t)E * 4));
    float* h1      = (float*)(ws + alloc((size_t)N * NHID * 4));   // reused as h2
    float* agg1    = (float*)(ws + alloc((size_t)N * NHID * 4));
    float* h2      = h1;
    float* out     = (float*)d_out;

    int nb_n = (N + 255) / 256;
    int nb_e = (E + 255) / 256;
    int nb_scan = (N + SCAN_CHUNK - 1) / SCAN_CHUNK;  // 98

    zero_cnt_k<<<nb_n, 256, 0, stream>>>(cnt, N);
    hist_k<<<nb_e, 256, 0, stream>>>(ei, cnt, E);
    dis_k<<<nb_n, 256, 0, stream>>>(cnt, dis, N);
    scanA_k<<<nb_scan, 256, 0, stream>>>(cnt, bsum, N);
    scanB_k<<<1, 256, 0, stream>>>(bsum, boff, nb_scan);
    scanC_k<<<nb_scan, 256, 0, stream>>>(cnt, boff, offs, cursor, N, E);
    fill_k<<<nb_e, 256, 0, stream>>>(ei, dis, cursor, csr_src, csr_w, E);

    dim3 g1((N + BM - 1) / BM, NHID / BN);
    gemm1_k<<<g1, 256, 0, stream>>>(x, W1, h1, N);
    agg1_k<<<N, 256, 0, stream>>>(h1, offs, csr_src, csr_w, dis, b1, agg1, N);

    gemm2_k<<<((size_t)N * NCLASS + 255) / 256, 256, 0, stream>>>(agg1, W2, h2, N);
    agg2_k<<<(N + 3) / 4, 256, 0, stream>>>(h2, offs, csr_src, csr_w, dis, b2, out, N);
    lsm_k<<<(N + 3) / 4, 256, 0, stream>>>(out, N);
}

// Round 4
// 1313.144 us; speedup vs baseline: 1.6462x; 1.6462x over previous
//
#include <hip/hip_runtime.h>
#include <math.h>

#define NFEAT 512
#define NHID  256
#define NCLASS 40
#define SCAN_CHUNK 1024

typedef __attribute__((ext_vector_type(8))) short short8;
typedef __attribute__((ext_vector_type(4))) float f32x4;

// ---------------- bf16 helpers ----------------

__device__ __forceinline__ float bflo(unsigned u) {
    union { unsigned i; float f; } x; x.i = u << 16; return x.f;
}
__device__ __forceinline__ float bfhi(unsigned u) {
    union { unsigned i; float f; } x; x.i = u & 0xffff0000u; return x.f;
}
__device__ __forceinline__ unsigned short f2bf(float f) {
    union { float f; unsigned i; } x; x.f = f;
    unsigned r = x.i + 0x7fffu + ((x.i >> 16) & 1u);   // round-to-nearest-even
    return (unsigned short)(r >> 16);
}
__device__ __forceinline__ unsigned pack2(float a, float b) {
    return (unsigned)f2bf(a) | ((unsigned)f2bf(b) << 16);
}

// ---------------- degree / norm ----------------

__global__ void zero_cnt_k(int* cnt, int n) {
    int i = blockIdx.x * 256 + threadIdx.x;
    if (i < n) cnt[i] = 0;
}

// harness stages integer inputs as int32
__global__ void hist_k(const int* __restrict__ ei, int* cnt, int E) {
    int e = blockIdx.x * 256 + threadIdx.x;
    if (e < E) atomicAdd(&cnt[ei[(size_t)E + e]], 1);
}

__global__ void dis_k(const int* __restrict__ cnt, float* dis, int n) {
    int i = blockIdx.x * 256 + threadIdx.x;
    if (i < n) dis[i] = rsqrtf((float)cnt[i] + 1.0f);
}

// ---------------- exclusive scan (3 kernels) ----------------

__global__ void scanA_k(const int* __restrict__ cnt, int* bsum, int n) {
    __shared__ int sd[256];
    int t = threadIdx.x;
    int base = blockIdx.x * SCAN_CHUNK + t * 4;
    int s = 0;
#pragma unroll
    for (int r = 0; r < 4; ++r) { int i = base + r; if (i < n) s += cnt[i]; }
    sd[t] = s;
    __syncthreads();
    for (int off = 128; off > 0; off >>= 1) {
        if (t < off) sd[t] += sd[t + off];
        __syncthreads();
    }
    if (t == 0) bsum[blockIdx.x] = sd[0];
}

__global__ void scanB_k(const int* __restrict__ bsum, int* boff, int nb) {
    __shared__ int sd[256];
    int t = threadIdx.x;
    int v = (t < nb) ? bsum[t] : 0;
    sd[t] = v;
    __syncthreads();
    for (int off = 1; off < 256; off <<= 1) {
        int add = (t >= off) ? sd[t - off] : 0;
        __syncthreads();
        sd[t] += add;
        __syncthreads();
    }
    if (t < nb) boff[t] = sd[t] - v;
}

__global__ void scanC_k(const int* __restrict__ cnt, const int* __restrict__ boff,
                        int* offs, int* cursor, int n, int E) {
    __shared__ int sd[256];
    int t = threadIdx.x, b = blockIdx.x;
    int base = b * SCAN_CHUNK + t * 4;
    int v[4];
    int s = 0;
#pragma unroll
    for (int r = 0; r < 4; ++r) {
        int i = base + r;
        v[r] = (i < n) ? cnt[i] : 0;
        s += v[r];
    }
    sd[t] = s;
    __syncthreads();
    for (int off = 1; off < 256; off <<= 1) {
        int add = (t >= off) ? sd[t - off] : 0;
        __syncthreads();
        sd[t] += add;
        __syncthreads();
    }
    int pos = boff[b] + (sd[t] - s);
#pragma unroll
    for (int r = 0; r < 4; ++r) {
        int i = base + r;
        if (i < n) { offs[i] = pos; cursor[i] = pos; }
        pos += v[r];
    }
    if (b == 0 && t == 0) offs[n] = E;
}

__global__ void fill_k(const int* __restrict__ ei, const float* __restrict__ dis,
                       int* cursor, int* csr_src, float* csr_w, int E) {
    int e = blockIdx.x * 256 + threadIdx.x;
    if (e < E) {
        int s = ei[e];
        int d = ei[(size_t)E + e];
        int pos = atomicAdd(&cursor[d], 1);
        csr_src[pos] = s;
        csr_w[pos] = dis[s] * dis[d];
    }
}

// ---------------- W1 transpose + cast: WT[n][k] = bf16(W1[k][n]) ----------------

__global__ void castw1_k(const float* __restrict__ W1, unsigned short* __restrict__ WT) {
    int idx = blockIdx.x * 256 + threadIdx.x;
    if (idx < NFEAT * NHID) {
        int k = idx >> 8;          // 0..511
        int nn = idx & 255;        // 0..255
        WT[(size_t)nn * NFEAT + k] = f2bf(W1[idx]);
    }
}

// ---------------- GEMM1: H(bf16) = X(Mx512 fp32→bf16) * W1, MFMA ----------------
// block 256 thr = 4 waves; tile 64(M) x 256(N) full-N; BK=64.
// wave w computes rows [0,64) x cols [w*64, w*64+64): 4x4 grid of 16x16 mfma.

__global__ __launch_bounds__(256) void gemm1_k(const float* __restrict__ X,
                                               const unsigned short* __restrict__ WT,
                                               unsigned short* __restrict__ H, int M) {
    __shared__ unsigned short as[64][72];   // [m][k], +8 pad (16B) keeps alignment
    __shared__ unsigned short bs[256][72];  // [n][k]
    int t = threadIdx.x;
    int lane = t & 63;
    int w = t >> 6;
    int m0 = blockIdx.x * 64;
    int quad = lane >> 4;
    int r16 = lane & 15;

    f32x4 acc[4][4];
#pragma unroll
    for (int a = 0; a < 4; ++a)
#pragma unroll
        for (int b = 0; b < 4; ++b) acc[a][b] = (f32x4){0.f, 0.f, 0.f, 0.f};

    for (int k0 = 0; k0 < NFEAT; k0 += 64) {
        // ---- stage A: thread t loads 16 floats of row m=t>>2, converts to bf16
        {
            int m = t >> 2;
            int c = (t & 3) * 16;
            int gi = m0 + m;
            float4 v0, v1, v2, v3;
            if (gi < M) {
                const float4* p = (const float4*)(X + (size_t)gi * NFEAT + k0 + c);
                v0 = p[0]; v1 = p[1]; v2 = p[2]; v3 = p[3];
            } else {
                v0 = v1 = v2 = v3 = make_float4(0.f, 0.f, 0.f, 0.f);
            }
            uint4 p0, p1;
            p0.x = pack2(v0.x, v0.y); p0.y = pack2(v0.z, v0.w);
            p0.z = pack2(v1.x, v1.y); p0.w = pack2(v1.z, v1.w);
            p1.x = pack2(v2.x, v2.y); p1.y = pack2(v2.z, v2.w);
            p1.z = pack2(v3.x, v3.y); p1.w = pack2(v3.z, v3.w);
            *(uint4*)&as[m][c] = p0;
            *(uint4*)&as[m][c + 8] = p1;
        }
        // ---- stage B: thread t loads 64 bf16 of WT row n=t (k contiguous)
        // 64 bf16 = 128 B = 8 x uint4  (R3 bug: only 4 loads -> half tile garbage)
        {
            const uint4* p = (const uint4*)(WT + (size_t)t * NFEAT + k0);
#pragma unroll
            for (int c = 0; c < 8; ++c) {
                uint4 q = p[c];
                *(uint4*)&bs[t][c * 8] = q;
            }
        }
        __syncthreads();
#pragma unroll
        for (int ks = 0; ks < 64; ks += 32) {
            short8 af[4], bfr[4];
#pragma unroll
            for (int sm = 0; sm < 4; ++sm)
                af[sm] = *(const short8*)&as[sm * 16 + r16][ks + quad * 8];
#pragma unroll
            for (int sn = 0; sn < 4; ++sn)
                bfr[sn] = *(const short8*)&bs[w * 64 + sn * 16 + r16][ks + quad * 8];
#pragma unroll
            for (int sm = 0; sm < 4; ++sm)
#pragma unroll
                for (int sn = 0; sn < 4; ++sn)
                    acc[sm][sn] = __builtin_amdgcn_mfma_f32_16x16x32_bf16(
                        af[sm], bfr[sn], acc[sm][sn], 0, 0, 0);
        }
        __syncthreads();
    }
    // epilogue: C/D mapping row=quad*4+r, col=lane&15 (m89-verified)
#pragma unroll
    for (int sm = 0; sm < 4; ++sm) {
#pragma unroll
        for (int rr = 0; rr < 4; ++rr) {
            int row = m0 + sm * 16 + quad * 4 + rr;
            if (row < M) {
#pragma unroll
                for (int sn = 0; sn < 4; ++sn) {
                    int col = w * 64 + sn * 16 + r16;
                    H[(size_t)row * NHID + col] = f2bf(acc[sm][sn][rr]);
                }
            }
        }
    }
}

// ---------------- agg1: wave per node, bf16 gathers, +bias +relu, bf16 out ----------------

__global__ __launch_bounds__(256) void agg1_k(const unsigned short* __restrict__ Hb,
                                              const int* __restrict__ offs,
                                              const int* __restrict__ csr_src,
                                              const float* __restrict__ csr_w,
                                              const float* __restrict__ dis,
                                              const float* __restrict__ b1,
                                              unsigned short* __restrict__ outb, int n) {
    int lane = threadIdx.x & 63;
    int i = blockIdx.x * 4 + (threadIdx.x >> 6);
    if (i >= n) return;
    const uint2* Hv = (const uint2*)Hb;   // row = 64 uint2 (256 bf16)
    float a0 = 0.f, a1 = 0.f, a2 = 0.f, a3 = 0.f;
    int beg = offs[i], end = offs[i + 1];
    for (int e = beg; e < end; ++e) {
        int s = csr_src[e];
        float wgt = csr_w[e];
        uint2 v = Hv[(size_t)s * 64 + lane];
        a0 += wgt * bflo(v.x); a1 += wgt * bfhi(v.x);
        a2 += wgt * bflo(v.y); a3 += wgt * bfhi(v.y);
    }
    float di = dis[i];
    float wsl = di * di;
    uint2 v = Hv[(size_t)i * 64 + lane];
    a0 += wsl * bflo(v.x); a1 += wsl * bfhi(v.x);
    a2 += wsl * bflo(v.y); a3 += wsl * bfhi(v.y);
    float4 bb = ((const float4*)b1)[lane];
    a0 = fmaxf(a0 + bb.x, 0.f); a1 = fmaxf(a1 + bb.y, 0.f);
    a2 = fmaxf(a2 + bb.z, 0.f); a3 = fmaxf(a3 + bb.w, 0.f);
    uint2 o;
    o.x = pack2(a0, a1);
    o.y = pack2(a2, a3);
    ((uint2*)outb)[(size_t)i * 64 + lane] = o;
}

// ---------------- GEMM2: H2(fp32) = A(bf16 Mx256) * W2(256x40 fp32) ----------------
// block 256 thr = 32 nodes x 8 class-groups of 5; W2 transposed in LDS (pad 260).

__global__ __launch_bounds__(256) void gemm2_k(const unsigned short* __restrict__ Ab,
                                               const float* __restrict__ W2,
                                               float* __restrict__ H2, int M) {
    __shared__ float w2t[NCLASS][260];
    int t = threadIdx.x;
    for (int idx = t; idx < NHID * NCLASS; idx += 256) {
        int k = idx / NCLASS;
        int j = idx - k * NCLASS;
        w2t[j][k] = W2[idx];
    }
    __syncthreads();
    int i = blockIdx.x * 32 + (t >> 3);
    if (i >= M) return;
    int j0 = (t & 7) * 5;
    const uint2* arow = (const uint2*)(Ab + (size_t)i * NHID);
    float acc[5] = {0.f, 0.f, 0.f, 0.f, 0.f};
#pragma unroll 4
    for (int c = 0; c < 64; ++c) {
        uint2 v = arow[c];
        float a0 = bflo(v.x), a1 = bfhi(v.x), a2 = bflo(v.y), a3 = bfhi(v.y);
        int k = c * 4;
#pragma unroll
        for (int jj = 0; jj < 5; ++jj) {
            float4 q = *(const float4*)&w2t[j0 + jj][k];
            acc[jj] += a0 * q.x + a1 * q.y + a2 * q.z + a3 * q.w;
        }
    }
#pragma unroll
    for (int jj = 0; jj < 5; ++jj) H2[(size_t)i * NCLASS + j0 + jj] = acc[jj];
}

// ---------------- aggregation layer 2 (40 feat) + bias ----------------

__global__ __launch_bounds__(256) void agg2_k(const float* __restrict__ H2,
                                              const int* __restrict__ offs,
                                              const int* __restrict__ csr_src,
                                              const float* __restrict__ csr_w,
                                              const float* __restrict__ dis,
                                              const float* __restrict__ b2,
                                              float* __restrict__ out, int n) {
    int i = blockIdx.x * 4 + (threadIdx.x >> 6);
    int j = threadIdx.x & 63;
    if (i >= n || j >= NCLASS) return;
    int beg = offs[i], end = offs[i + 1];
    float acc = 0.0f;
    for (int e = beg; e < end; ++e) {
        acc += csr_w[e] * H2[(size_t)csr_src[e] * NCLASS + j];
    }
    float di = dis[i];
    acc += di * di * H2[(size_t)i * NCLASS + j];
    acc += b2[j];
    out[(size_t)i * NCLASS + j] = acc;
}

// ---------------- log_softmax per row ----------------

__global__ __launch_bounds__(256) void lsm_k(float* __restrict__ out, int n) {
    int i = blockIdx.x * 4 + (threadIdx.x >> 6);
    int j = threadIdx.x & 63;
    if (i >= n) return;
    float v = (j < NCLASS) ? out[(size_t)i * NCLASS + j] : -INFINITY;
    float m = v;
#pragma unroll
    for (int off = 32; off > 0; off >>= 1) m = fmaxf(m, __shfl_xor(m, off, 64));
    float e = (j < NCLASS) ? expf(v - m) : 0.0f;
    float s = e;
#pragma unroll
    for (int off = 32; off > 0; off >>= 1) s += __shfl_xor(s, off, 64);
    if (j < NCLASS) out[(size_t)i * NCLASS + j] = v - m - logf(s);
}

// ---------------- launch ----------------

extern "C" void kernel_launch(void* const* d_in, const int* in_sizes, int n_in,
                              void* d_out, int out_size, void* d_ws, size_t ws_size,
                              hipStream_t stream) {
    const float* x  = (const float*)d_in[0];
    const float* W1 = (const float*)d_in[1];
    const float* b1 = (const float*)d_in[2];
    const float* W2 = (const float*)d_in[3];
    const float* b2 = (const float*)d_in[4];
    const int*   ei = (const int*)d_in[5];   // int32-staged

    const int N = in_sizes[0] / NFEAT;      // 100000
    const int E = in_sizes[5] / 2;          // 3200000

    size_t off = 0;
    auto alloc = [&](size_t bytes) { size_t o = off; off += (bytes + 255) & ~(size_t)255; return o; };
    char* ws = (char*)d_ws;
    int*            cnt     = (int*)           (ws + alloc((size_t)N * 4));
    int*            offs    = (int*)           (ws + alloc((size_t)(N + 1) * 4));
    int*            cursor  = (int*)           (ws + alloc((size_t)N * 4));
    float*          dis     = (float*)         (ws + alloc((size_t)N * 4));
    int*            bsum    = (int*)           (ws + alloc(256 * 4));
    int*            boff    = (int*)           (ws + alloc(256 * 4));
    int*            csr_src = (int*)           (ws + alloc((size_t)E * 4));
    float*          csr_w   = (float*)         (ws + alloc((size_t)E * 4));
    unsigned short* wT      = (unsigned short*)(ws + alloc((size_t)NFEAT * NHID * 2));
    unsigned short* h1b     = (unsigned short*)(ws + alloc((size_t)N * NHID * 2));
    unsigned short* a1b     = (unsigned short*)(ws + alloc((size_t)N * NHID * 2));
    float*          h2      = (float*)         (ws + alloc((size_t)N * NCLASS * 4));
    float*          out     = (float*)d_out;

    int nb_n = (N + 255) / 256;
    int nb_e = (E + 255) / 256;
    int nb_scan = (N + SCAN_CHUNK - 1) / SCAN_CHUNK;

    zero_cnt_k<<<nb_n, 256, 0, stream>>>(cnt, N);
    hist_k<<<nb_e, 256, 0, stream>>>(ei, cnt, E);
    dis_k<<<nb_n, 256, 0, stream>>>(cnt, dis, N);
    scanA_k<<<nb_scan, 256, 0, stream>>>(cnt, bsum, N);
    scanB_k<<<1, 256, 0, stream>>>(bsum, boff, nb_scan);
    scanC_k<<<nb_scan, 256, 0, stream>>>(cnt, boff, offs, cursor, N, E);
    fill_k<<<nb_e, 256, 0, stream>>>(ei, dis, cursor, csr_src, csr_w, E);

    castw1_k<<<(NFEAT * NHID + 255) / 256, 256, 0, stream>>>(W1, wT);
    gemm1_k<<<(N + 63) / 64, 256, 0, stream>>>(x, wT, h1b, N);
    agg1_k<<<(N + 3) / 4, 256, 0, stream>>>(h1b, offs, csr_src, csr_w, dis, b1, a1b, N);
    gemm2_k<<<(N + 31) / 32, 256, 0, stream>>>(a1b, W2, h2, N);
    agg2_k<<<(N + 3) / 4, 256, 0, stream>>>(h2, offs, csr_src, csr_w, dis, b2, out, N);
    lsm_k<<<(N + 3) / 4, 256, 0, stream>>>(out, N);
}

// Round 5
// 1052.091 us; speedup vs baseline: 2.0547x; 1.2481x over previous
//
#include <hip/hip_runtime.h>
#include <math.h>

#define NFEAT 512
#define NHID  256
#define NCLASS 40
#define SCAN_CHUNK 1024

typedef __attribute__((ext_vector_type(8))) short short8;
typedef __attribute__((ext_vector_type(4))) float f32x4;

// ---------------- bf16 helpers ----------------

__device__ __forceinline__ float bflo(unsigned u) {
    union { unsigned i; float f; } x; x.i = u << 16; return x.f;
}
__device__ __forceinline__ float bfhi(unsigned u) {
    union { unsigned i; float f; } x; x.i = u & 0xffff0000u; return x.f;
}
__device__ __forceinline__ unsigned short f2bf(float f) {
    union { float f; unsigned i; } x; x.f = f;
    unsigned r = x.i + 0x7fffu + ((x.i >> 16) & 1u);   // round-to-nearest-even
    return (unsigned short)(r >> 16);
}
__device__ __forceinline__ unsigned pack2(float a, float b) {
    return (unsigned)f2bf(a) | ((unsigned)f2bf(b) << 16);
}

// ---------------- degree / norm ----------------

__global__ void zero_cnt_k(int* cnt, int n) {
    int i = blockIdx.x * 256 + threadIdx.x;
    if (i < n) cnt[i] = 0;
}

// harness stages integer inputs as int32
__global__ void hist_k(const int* __restrict__ ei, int* cnt, int E) {
    int e = blockIdx.x * 256 + threadIdx.x;
    if (e < E) atomicAdd(&cnt[ei[(size_t)E + e]], 1);
}

__global__ void dis_k(const int* __restrict__ cnt, float* dis, int n) {
    int i = blockIdx.x * 256 + threadIdx.x;
    if (i < n) dis[i] = rsqrtf((float)cnt[i] + 1.0f);
}

// ---------------- exclusive scan (3 kernels) ----------------

__global__ void scanA_k(const int* __restrict__ cnt, int* bsum, int n) {
    __shared__ int sd[256];
    int t = threadIdx.x;
    int base = blockIdx.x * SCAN_CHUNK + t * 4;
    int s = 0;
#pragma unroll
    for (int r = 0; r < 4; ++r) { int i = base + r; if (i < n) s += cnt[i]; }
    sd[t] = s;
    __syncthreads();
    for (int off = 128; off > 0; off >>= 1) {
        if (t < off) sd[t] += sd[t + off];
        __syncthreads();
    }
    if (t == 0) bsum[blockIdx.x] = sd[0];
}

__global__ void scanB_k(const int* __restrict__ bsum, int* boff, int nb) {
    __shared__ int sd[256];
    int t = threadIdx.x;
    int v = (t < nb) ? bsum[t] : 0;
    sd[t] = v;
    __syncthreads();
    for (int off = 1; off < 256; off <<= 1) {
        int add = (t >= off) ? sd[t - off] : 0;
        __syncthreads();
        sd[t] += add;
        __syncthreads();
    }
    if (t < nb) boff[t] = sd[t] - v;
}

__global__ void scanC_k(const int* __restrict__ cnt, const int* __restrict__ boff,
                        int* offs, int* cursor, int n, int E) {
    __shared__ int sd[256];
    int t = threadIdx.x, b = blockIdx.x;
    int base = b * SCAN_CHUNK + t * 4;
    int v[4];
    int s = 0;
#pragma unroll
    for (int r = 0; r < 4; ++r) {
        int i = base + r;
        v[r] = (i < n) ? cnt[i] : 0;
        s += v[r];
    }
    sd[t] = s;
    __syncthreads();
    for (int off = 1; off < 256; off <<= 1) {
        int add = (t >= off) ? sd[t - off] : 0;
        __syncthreads();
        sd[t] += add;
        __syncthreads();
    }
    int pos = boff[b] + (sd[t] - s);
#pragma unroll
    for (int r = 0; r < 4; ++r) {
        int i = base + r;
        if (i < n) { offs[i] = pos; cursor[i] = pos; }
        pos += v[r];
    }
    if (b == 0 && t == 0) offs[n] = E;
}

// interleaved CSR entry: {src, weight bits} — one 8-B store per edge
__global__ void fill_k(const int* __restrict__ ei, const float* __restrict__ dis,
                       int* cursor, uint2* __restrict__ csr, int E) {
    int e = blockIdx.x * 256 + threadIdx.x;
    if (e < E) {
        int s = ei[e];
        int d = ei[(size_t)E + e];
        int pos = atomicAdd(&cursor[d], 1);
        float w = dis[s] * dis[d];
        csr[pos] = make_uint2((unsigned)s, __float_as_uint(w));
    }
}

// ---------------- W1 transpose + cast: WT[n][k] = bf16(W1[k][n]) ----------------

__global__ void castw1_k(const float* __restrict__ W1, unsigned short* __restrict__ WT) {
    int idx = blockIdx.x * 256 + threadIdx.x;
    if (idx < NFEAT * NHID) {
        int k = idx >> 8;
        int nn = idx & 255;
        WT[(size_t)nn * NFEAT + k] = f2bf(W1[idx]);
    }
}

// ---------------- GEMM1: H(bf16) = X(Mx512 fp32→bf16) * W1, MFMA ----------------

__global__ __launch_bounds__(256) void gemm1_k(const float* __restrict__ X,
                                               const unsigned short* __restrict__ WT,
                                               unsigned short* __restrict__ H, int M) {
    __shared__ unsigned short as[64][72];
    __shared__ unsigned short bs[256][72];
    int t = threadIdx.x;
    int lane = t & 63;
    int w = t >> 6;
    int m0 = blockIdx.x * 64;
    int quad = lane >> 4;
    int r16 = lane & 15;

    f32x4 acc[4][4];
#pragma unroll
    for (int a = 0; a < 4; ++a)
#pragma unroll
        for (int b = 0; b < 4; ++b) acc[a][b] = (f32x4){0.f, 0.f, 0.f, 0.f};

    for (int k0 = 0; k0 < NFEAT; k0 += 64) {
        {
            int m = t >> 2;
            int c = (t & 3) * 16;
            int gi = m0 + m;
            float4 v0, v1, v2, v3;
            if (gi < M) {
                const float4* p = (const float4*)(X + (size_t)gi * NFEAT + k0 + c);
                v0 = p[0]; v1 = p[1]; v2 = p[2]; v3 = p[3];
            } else {
                v0 = v1 = v2 = v3 = make_float4(0.f, 0.f, 0.f, 0.f);
            }
            uint4 p0, p1;
            p0.x = pack2(v0.x, v0.y); p0.y = pack2(v0.z, v0.w);
            p0.z = pack2(v1.x, v1.y); p0.w = pack2(v1.z, v1.w);
            p1.x = pack2(v2.x, v2.y); p1.y = pack2(v2.z, v2.w);
            p1.z = pack2(v3.x, v3.y); p1.w = pack2(v3.z, v3.w);
            *(uint4*)&as[m][c] = p0;
            *(uint4*)&as[m][c + 8] = p1;
        }
        {
            const uint4* p = (const uint4*)(WT + (size_t)t * NFEAT + k0);
#pragma unroll
            for (int c = 0; c < 8; ++c) {
                uint4 q = p[c];
                *(uint4*)&bs[t][c * 8] = q;
            }
        }
        __syncthreads();
#pragma unroll
        for (int ks = 0; ks < 64; ks += 32) {
            short8 af[4], bfr[4];
#pragma unroll
            for (int sm = 0; sm < 4; ++sm)
                af[sm] = *(const short8*)&as[sm * 16 + r16][ks + quad * 8];
#pragma unroll
            for (int sn = 0; sn < 4; ++sn)
                bfr[sn] = *(const short8*)&bs[w * 64 + sn * 16 + r16][ks + quad * 8];
#pragma unroll
            for (int sm = 0; sm < 4; ++sm)
#pragma unroll
                for (int sn = 0; sn < 4; ++sn)
                    acc[sm][sn] = __builtin_amdgcn_mfma_f32_16x16x32_bf16(
                        af[sm], bfr[sn], acc[sm][sn], 0, 0, 0);
        }
        __syncthreads();
    }
#pragma unroll
    for (int sm = 0; sm < 4; ++sm) {
#pragma unroll
        for (int rr = 0; rr < 4; ++rr) {
            int row = m0 + sm * 16 + quad * 4 + rr;
            if (row < M) {
#pragma unroll
                for (int sn = 0; sn < 4; ++sn) {
                    int col = w * 64 + sn * 16 + r16;
                    H[(size_t)row * NHID + col] = f2bf(acc[sm][sn][rr]);
                }
            }
        }
    }
}

// ---------------- agg1: wave/node, 8-deep gather pipeline, bf16 in/out ----------------

__global__ __launch_bounds__(256) void agg1_k(const unsigned short* __restrict__ Hb,
                                              const int* __restrict__ offs,
                                              const uint2* __restrict__ csr,
                                              const float* __restrict__ dis,
                                              const float* __restrict__ b1,
                                              unsigned short* __restrict__ outb, int n) {
    int lane = threadIdx.x & 63;
    int i = blockIdx.x * 4 + (threadIdx.x >> 6);
    if (i >= n) return;
    const uint2* Hv = (const uint2*)Hb;   // row = 64 uint2 (256 bf16)
    float a0 = 0.f, a1 = 0.f, a2 = 0.f, a3 = 0.f;
    int beg = offs[i], end = offs[i + 1];
    int e = beg;
    for (; e + 8 <= end; e += 8) {
        uint2 c0 = csr[e + 0], c1 = csr[e + 1], c2 = csr[e + 2], c3 = csr[e + 3];
        uint2 c4 = csr[e + 4], c5 = csr[e + 5], c6 = csr[e + 6], c7 = csr[e + 7];
        uint2 g0 = Hv[(size_t)c0.x * 64 + lane];
        uint2 g1 = Hv[(size_t)c1.x * 64 + lane];
        uint2 g2 = Hv[(size_t)c2.x * 64 + lane];
        uint2 g3 = Hv[(size_t)c3.x * 64 + lane];
        uint2 g4 = Hv[(size_t)c4.x * 64 + lane];
        uint2 g5 = Hv[(size_t)c5.x * 64 + lane];
        uint2 g6 = Hv[(size_t)c6.x * 64 + lane];
        uint2 g7 = Hv[(size_t)c7.x * 64 + lane];
        float w0 = __uint_as_float(c0.y), w1 = __uint_as_float(c1.y);
        float w2 = __uint_as_float(c2.y), w3 = __uint_as_float(c3.y);
        float w4 = __uint_as_float(c4.y), w5 = __uint_as_float(c5.y);
        float w6 = __uint_as_float(c6.y), w7 = __uint_as_float(c7.y);
        a0 += w0 * bflo(g0.x); a1 += w0 * bfhi(g0.x); a2 += w0 * bflo(g0.y); a3 += w0 * bfhi(g0.y);
        a0 += w1 * bflo(g1.x); a1 += w1 * bfhi(g1.x); a2 += w1 * bflo(g1.y); a3 += w1 * bfhi(g1.y);
        a0 += w2 * bflo(g2.x); a1 += w2 * bfhi(g2.x); a2 += w2 * bflo(g2.y); a3 += w2 * bfhi(g2.y);
        a0 += w3 * bflo(g3.x); a1 += w3 * bfhi(g3.x); a2 += w3 * bflo(g3.y); a3 += w3 * bfhi(g3.y);
        a0 += w4 * bflo(g4.x); a1 += w4 * bfhi(g4.x); a2 += w4 * bflo(g4.y); a3 += w4 * bfhi(g4.y);
        a0 += w5 * bflo(g5.x); a1 += w5 * bfhi(g5.x); a2 += w5 * bflo(g5.y); a3 += w5 * bfhi(g5.y);
        a0 += w6 * bflo(g6.x); a1 += w6 * bfhi(g6.x); a2 += w6 * bflo(g6.y); a3 += w6 * bfhi(g6.y);
        a0 += w7 * bflo(g7.x); a1 += w7 * bfhi(g7.x); a2 += w7 * bflo(g7.y); a3 += w7 * bfhi(g7.y);
    }
    for (; e < end; ++e) {
        uint2 c = csr[e];
        uint2 g = Hv[(size_t)c.x * 64 + lane];
        float wgt = __uint_as_float(c.y);
        a0 += wgt * bflo(g.x); a1 += wgt * bfhi(g.x);
        a2 += wgt * bflo(g.y); a3 += wgt * bfhi(g.y);
    }
    float di = dis[i];
    float wsl = di * di;
    uint2 v = Hv[(size_t)i * 64 + lane];
    a0 += wsl * bflo(v.x); a1 += wsl * bfhi(v.x);
    a2 += wsl * bflo(v.y); a3 += wsl * bfhi(v.y);
    float4 bb = ((const float4*)b1)[lane];
    a0 = fmaxf(a0 + bb.x, 0.f); a1 = fmaxf(a1 + bb.y, 0.f);
    a2 = fmaxf(a2 + bb.z, 0.f); a3 = fmaxf(a3 + bb.w, 0.f);
    uint2 o;
    o.x = pack2(a0, a1);
    o.y = pack2(a2, a3);
    ((uint2*)outb)[(size_t)i * 64 + lane] = o;
}

// ---------------- GEMM2: H2(bf16 Mx40) = A(bf16 Mx256) * W2(256x40 fp32) ----------------

__global__ __launch_bounds__(256) void gemm2_k(const unsigned short* __restrict__ Ab,
                                               const float* __restrict__ W2,
                                               unsigned short* __restrict__ H2b, int M) {
    __shared__ float w2t[NCLASS][260];
    int t = threadIdx.x;
    for (int idx = t; idx < NHID * NCLASS; idx += 256) {
        int k = idx / NCLASS;
        int j = idx - k * NCLASS;
        w2t[j][k] = W2[idx];
    }
    __syncthreads();
    int i = blockIdx.x * 32 + (t >> 3);
    if (i >= M) return;
    int j0 = (t & 7) * 5;
    const uint2* arow = (const uint2*)(Ab + (size_t)i * NHID);
    float acc[5] = {0.f, 0.f, 0.f, 0.f, 0.f};
#pragma unroll 4
    for (int c = 0; c < 64; ++c) {
        uint2 v = arow[c];
        float a0 = bflo(v.x), a1 = bfhi(v.x), a2 = bflo(v.y), a3 = bfhi(v.y);
        int k = c * 4;
#pragma unroll
        for (int jj = 0; jj < 5; ++jj) {
            float4 q = *(const float4*)&w2t[j0 + jj][k];
            acc[jj] += a0 * q.x + a1 * q.y + a2 * q.z + a3 * q.w;
        }
    }
#pragma unroll
    for (int jj = 0; jj < 5; ++jj)
        H2b[(size_t)i * NCLASS + j0 + jj] = f2bf(acc[jj]);
}

// ---------------- agg2 + bias + fused log_softmax ----------------
// wave per node; lane jj<10 holds feats [4jj,4jj+4) as one uint2 (4 bf16).

__global__ __launch_bounds__(256) void agg2_k(const unsigned short* __restrict__ H2b,
                                              const int* __restrict__ offs,
                                              const uint2* __restrict__ csr,
                                              const float* __restrict__ dis,
                                              const float* __restrict__ b2,
                                              float* __restrict__ out, int n) {
    int lane = threadIdx.x & 63;
    int i = blockIdx.x * 4 + (threadIdx.x >> 6);
    if (i >= n) return;
    const uint2* Hv = (const uint2*)H2b;   // row = 10 uint2 (40 bf16)
    bool act = (lane < 10);
    int jc = act ? lane : 0;               // inactive lanes duplicate lane 0 (broadcast)
    float a0 = 0.f, a1 = 0.f, a2 = 0.f, a3 = 0.f;
    int beg = offs[i], end = offs[i + 1];
    int e = beg;
    for (; e + 4 <= end; e += 4) {
        uint2 c0 = csr[e + 0], c1 = csr[e + 1], c2 = csr[e + 2], c3 = csr[e + 3];
        uint2 g0 = Hv[(size_t)c0.x * 10 + jc];
        uint2 g1 = Hv[(size_t)c1.x * 10 + jc];
        uint2 g2 = Hv[(size_t)c2.x * 10 + jc];
        uint2 g3 = Hv[(size_t)c3.x * 10 + jc];
        float w0 = __uint_as_float(c0.y), w1 = __uint_as_float(c1.y);
        float w2 = __uint_as_float(c2.y), w3 = __uint_as_float(c3.y);
        a0 += w0 * bflo(g0.x); a1 += w0 * bfhi(g0.x); a2 += w0 * bflo(g0.y); a3 += w0 * bfhi(g0.y);
        a0 += w1 * bflo(g1.x); a1 += w1 * bfhi(g1.x); a2 += w1 * bflo(g1.y); a3 += w1 * bfhi(g1.y);
        a0 += w2 * bflo(g2.x); a1 += w2 * bfhi(g2.x); a2 += w2 * bflo(g2.y); a3 += w2 * bfhi(g2.y);
        a0 += w3 * bflo(g3.x); a1 += w3 * bfhi(g3.x); a2 += w3 * bflo(g3.y); a3 += w3 * bfhi(g3.y);
    }
    for (; e < end; ++e) {
        uint2 c = csr[e];
        uint2 g = Hv[(size_t)c.x * 10 + jc];
        float wgt = __uint_as_float(c.y);
        a0 += wgt * bflo(g.x); a1 += wgt * bfhi(g.x);
        a2 += wgt * bflo(g.y); a3 += wgt * bfhi(g.y);
    }
    float di = dis[i];
    float wsl = di * di;
    uint2 v = Hv[(size_t)i * 10 + jc];
    a0 += wsl * bflo(v.x); a1 += wsl * bfhi(v.x);
    a2 += wsl * bflo(v.y); a3 += wsl * bfhi(v.y);
    float4 bb = ((const float4*)b2)[jc];   // b2 has 40 floats, float4-aligned
    a0 += bb.x; a1 += bb.y; a2 += bb.z; a3 += bb.w;
    // log_softmax across the 40 values held by lanes 0..9 (shuffle width 16)
    float m = act ? fmaxf(fmaxf(a0, a1), fmaxf(a2, a3)) : -INFINITY;
#pragma unroll
    for (int off = 8; off > 0; off >>= 1) m = fmaxf(m, __shfl_xor(m, off, 16));
    float s = act ? (expf(a0 - m) + expf(a1 - m) + expf(a2 - m) + expf(a3 - m)) : 0.f;
#pragma unroll
    for (int off = 8; off > 0; off >>= 1) s += __shfl_xor(s, off, 16);
    float ls = m + logf(s);
    if (act) {
        float4 o = make_float4(a0 - ls, a1 - ls, a2 - ls, a3 - ls);
        ((float4*)(out + (size_t)i * NCLASS))[lane] = o;
    }
}

// ---------------- launch ----------------

extern "C" void kernel_launch(void* const* d_in, const int* in_sizes, int n_in,
                              void* d_out, int out_size, void* d_ws, size_t ws_size,
                              hipStream_t stream) {
    const float* x  = (const float*)d_in[0];
    const float* W1 = (const float*)d_in[1];
    const float* b1 = (const float*)d_in[2];
    const float* W2 = (const float*)d_in[3];
    const float* b2 = (const float*)d_in[4];
    const int*   ei = (const int*)d_in[5];   // int32-staged

    const int N = in_sizes[0] / NFEAT;      // 100000
    const int E = in_sizes[5] / 2;          // 3200000

    size_t off = 0;
    auto alloc = [&](size_t bytes) { size_t o = off; off += (bytes + 255) & ~(size_t)255; return o; };
    char* ws = (char*)d_ws;
    int*            cnt     = (int*)           (ws + alloc((size_t)N * 4));
    int*            offs    = (int*)           (ws + alloc((size_t)(N + 1) * 4));
    int*            cursor  = (int*)           (ws + alloc((size_t)N * 4));
    float*          dis     = (float*)         (ws + alloc((size_t)N * 4));
    int*            bsum    = (int*)           (ws + alloc(256 * 4));
    int*            boff    = (int*)           (ws + alloc(256 * 4));
    uint2*          csr     = (uint2*)         (ws + alloc((size_t)E * 8));
    unsigned short* wT      = (unsigned short*)(ws + alloc((size_t)NFEAT * NHID * 2));
    unsigned short* h1b     = (unsigned short*)(ws + alloc((size_t)N * NHID * 2));
    unsigned short* a1b     = (unsigned short*)(ws + alloc((size_t)N * NHID * 2));
    unsigned short* h2b     = (unsigned short*)(ws + alloc((size_t)N * NCLASS * 2));
    float*          out     = (float*)d_out;

    int nb_n = (N + 255) / 256;
    int nb_e = (E + 255) / 256;
    int nb_scan = (N + SCAN_CHUNK - 1) / SCAN_CHUNK;

    zero_cnt_k<<<nb_n, 256, 0, stream>>>(cnt, N);
    hist_k<<<nb_e, 256, 0, stream>>>(ei, cnt, E);
    dis_k<<<nb_n, 256, 0, stream>>>(cnt, dis, N);
    scanA_k<<<nb_scan, 256, 0, stream>>>(cnt, bsum, N);
    scanB_k<<<1, 256, 0, stream>>>(bsum, boff, nb_scan);
    scanC_k<<<nb_scan, 256, 0, stream>>>(cnt, boff, offs, cursor, N, E);
    fill_k<<<nb_e, 256, 0, stream>>>(ei, dis, cursor, csr, E);

    castw1_k<<<(NFEAT * NHID + 255) / 256, 256, 0, stream>>>(W1, wT);
    gemm1_k<<<(N + 63) / 64, 256, 0, stream>>>(x, wT, h1b, N);
    agg1_k<<<(N + 3) / 4, 256, 0, stream>>>(h1b, offs, csr, dis, b1, a1b, N);
    gemm2_k<<<(N + 31) / 32, 256, 0, stream>>>(a1b, W2, h2b, N);
    agg2_k<<<(N + 3) / 4, 256, 0, stream>>>(h2b, offs, csr, dis, b2, out, N);
}

// Round 6
// 972.927 us; speedup vs baseline: 2.2218x; 1.0814x over previous
//
#include <hip/hip_runtime.h>
#include <math.h>

#define NFEAT 512
#define NHID  256
#define NCLASS 40
#define SCAN_CHUNK 1024

typedef __attribute__((ext_vector_type(8))) short short8;
typedef __attribute__((ext_vector_type(4))) float f32x4;

// ---------------- bf16 helpers ----------------

__device__ __forceinline__ float bflo(unsigned u) {
    union { unsigned i; float f; } x; x.i = u << 16; return x.f;
}
__device__ __forceinline__ float bfhi(unsigned u) {
    union { unsigned i; float f; } x; x.i = u & 0xffff0000u; return x.f;
}
__device__ __forceinline__ unsigned short f2bf(float f) {
    union { float f; unsigned i; } x; x.f = f;
    unsigned r = x.i + 0x7fffu + ((x.i >> 16) & 1u);   // round-to-nearest-even
    return (unsigned short)(r >> 16);
}
__device__ __forceinline__ unsigned pack2(float a, float b) {
    return (unsigned)f2bf(a) | ((unsigned)f2bf(b) << 16);
}

// ---------------- degree ----------------

// harness stages integer inputs as int32
__global__ void hist_k(const int* __restrict__ ei, int* cnt, int E) {
    int e = blockIdx.x * 256 + threadIdx.x;
    if (e < E) atomicAdd(&cnt[ei[(size_t)E + e]], 1);
}

// ---------------- exclusive scan (3 kernels); scanA also emits dis ----------------

__global__ void scanA_k(const int* __restrict__ cnt, int* bsum, float* dis, int n) {
    __shared__ int sd[256];
    int t = threadIdx.x;
    int base = blockIdx.x * SCAN_CHUNK + t * 4;
    int s = 0;
#pragma unroll
    for (int r = 0; r < 4; ++r) {
        int i = base + r;
        if (i < n) {
            int c = cnt[i];
            s += c;
            dis[i] = rsqrtf((float)c + 1.0f);   // +1 self loop
        }
    }
    sd[t] = s;
    __syncthreads();
    for (int off = 128; off > 0; off >>= 1) {
        if (t < off) sd[t] += sd[t + off];
        __syncthreads();
    }
    if (t == 0) bsum[blockIdx.x] = sd[0];
}

__global__ void scanB_k(const int* __restrict__ bsum, int* boff, int nb) {
    __shared__ int sd[256];
    int t = threadIdx.x;
    int v = (t < nb) ? bsum[t] : 0;
    sd[t] = v;
    __syncthreads();
    for (int off = 1; off < 256; off <<= 1) {
        int add = (t >= off) ? sd[t - off] : 0;
        __syncthreads();
        sd[t] += add;
        __syncthreads();
    }
    if (t < nb) boff[t] = sd[t] - v;
}

__global__ void scanC_k(const int* __restrict__ cnt, const int* __restrict__ boff,
                        int* offs, int* cursor, int n, int E) {
    __shared__ int sd[256];
    int t = threadIdx.x, b = blockIdx.x;
    int base = b * SCAN_CHUNK + t * 4;
    int v[4];
    int s = 0;
#pragma unroll
    for (int r = 0; r < 4; ++r) {
        int i = base + r;
        v[r] = (i < n) ? cnt[i] : 0;
        s += v[r];
    }
    sd[t] = s;
    __syncthreads();
    for (int off = 1; off < 256; off <<= 1) {
        int add = (t >= off) ? sd[t - off] : 0;
        __syncthreads();
        sd[t] += add;
        __syncthreads();
    }
    int pos = boff[b] + (sd[t] - s);
#pragma unroll
    for (int r = 0; r < 4; ++r) {
        int i = base + r;
        if (i < n) { offs[i] = pos; cursor[i] = pos; }
        pos += v[r];
    }
    if (b == 0 && t == 0) offs[n] = E;
}

// interleaved CSR entry: {src, weight bits} — one 8-B store per edge
__global__ void fill_k(const int* __restrict__ ei, const float* __restrict__ dis,
                       int* cursor, uint2* __restrict__ csr, int E) {
    int e = blockIdx.x * 256 + threadIdx.x;
    if (e < E) {
        int s = ei[e];
        int d = ei[(size_t)E + e];
        int pos = atomicAdd(&cursor[d], 1);
        float w = dis[s] * dis[d];
        csr[pos] = make_uint2((unsigned)s, __float_as_uint(w));
    }
}

// ---------------- W1 transpose + cast: WT[n][k] = bf16(W1[k][n]) ----------------

__global__ void castw1_k(const float* __restrict__ W1, unsigned short* __restrict__ WT) {
    int idx = blockIdx.x * 256 + threadIdx.x;
    if (idx < NFEAT * NHID) {
        int k = idx >> 8;
        int nn = idx & 255;
        WT[(size_t)nn * NFEAT + k] = f2bf(W1[idx]);
    }
}

// ---------------- GEMM1: H(bf16) = X(Mx512 fp32→bf16) * W1, MFMA ----------------

__global__ __launch_bounds__(256) void gemm1_k(const float* __restrict__ X,
                                               const unsigned short* __restrict__ WT,
                                               unsigned short* __restrict__ H, int M) {
    __shared__ unsigned short as[64][72];
    __shared__ unsigned short bs[256][72];
    int t = threadIdx.x;
    int lane = t & 63;
    int w = t >> 6;
    int m0 = blockIdx.x * 64;
    int quad = lane >> 4;
    int r16 = lane & 15;

    f32x4 acc[4][4];
#pragma unroll
    for (int a = 0; a < 4; ++a)
#pragma unroll
        for (int b = 0; b < 4; ++b) acc[a][b] = (f32x4){0.f, 0.f, 0.f, 0.f};

    for (int k0 = 0; k0 < NFEAT; k0 += 64) {
        {
            int m = t >> 2;
            int c = (t & 3) * 16;
            int gi = m0 + m;
            float4 v0, v1, v2, v3;
            if (gi < M) {
                const float4* p = (const float4*)(X + (size_t)gi * NFEAT + k0 + c);
                v0 = p[0]; v1 = p[1]; v2 = p[2]; v3 = p[3];
            } else {
                v0 = v1 = v2 = v3 = make_float4(0.f, 0.f, 0.f, 0.f);
            }
            uint4 p0, p1;
            p0.x = pack2(v0.x, v0.y); p0.y = pack2(v0.z, v0.w);
            p0.z = pack2(v1.x, v1.y); p0.w = pack2(v1.z, v1.w);
            p1.x = pack2(v2.x, v2.y); p1.y = pack2(v2.z, v2.w);
            p1.z = pack2(v3.x, v3.y); p1.w = pack2(v3.z, v3.w);
            *(uint4*)&as[m][c] = p0;
            *(uint4*)&as[m][c + 8] = p1;
        }
        {
            const uint4* p = (const uint4*)(WT + (size_t)t * NFEAT + k0);
#pragma unroll
            for (int c = 0; c < 8; ++c) {
                uint4 q = p[c];
                *(uint4*)&bs[t][c * 8] = q;
            }
        }
        __syncthreads();
#pragma unroll
        for (int ks = 0; ks < 64; ks += 32) {
            short8 af[4], bfr[4];
#pragma unroll
            for (int sm = 0; sm < 4; ++sm)
                af[sm] = *(const short8*)&as[sm * 16 + r16][ks + quad * 8];
#pragma unroll
            for (int sn = 0; sn < 4; ++sn)
                bfr[sn] = *(const short8*)&bs[w * 64 + sn * 16 + r16][ks + quad * 8];
#pragma unroll
            for (int sm = 0; sm < 4; ++sm)
#pragma unroll
                for (int sn = 0; sn < 4; ++sn)
                    acc[sm][sn] = __builtin_amdgcn_mfma_f32_16x16x32_bf16(
                        af[sm], bfr[sn], acc[sm][sn], 0, 0, 0);
        }
        __syncthreads();
    }
#pragma unroll
    for (int sm = 0; sm < 4; ++sm) {
#pragma unroll
        for (int rr = 0; rr < 4; ++rr) {
            int row = m0 + sm * 16 + quad * 4 + rr;
            if (row < M) {
#pragma unroll
                for (int sn = 0; sn < 4; ++sn) {
                    int col = w * 64 + sn * 16 + r16;
                    H[(size_t)row * NHID + col] = f2bf(acc[sm][sn][rr]);
                }
            }
        }
    }
}

// ---------------- agg1: wave/node, 16-deep gather pipeline, bf16 in/out ----------------

__global__ __launch_bounds__(256) void agg1_k(const unsigned short* __restrict__ Hb,
                                              const int* __restrict__ offs,
                                              const uint2* __restrict__ csr,
                                              const float* __restrict__ dis,
                                              const float* __restrict__ b1,
                                              unsigned short* __restrict__ outb, int n) {
    int lane = threadIdx.x & 63;
    int i = blockIdx.x * 4 + (threadIdx.x >> 6);
    if (i >= n) return;
    const uint2* Hv = (const uint2*)Hb;   // row = 64 uint2 (256 bf16)
    float a0 = 0.f, a1 = 0.f, a2 = 0.f, a3 = 0.f;
    int beg = offs[i], end = offs[i + 1];
    int e = beg;
    {
        uint2 c[16], g[16];
        for (; e + 16 <= end; e += 16) {
#pragma unroll
            for (int u = 0; u < 16; ++u) c[u] = csr[e + u];
#pragma unroll
            for (int u = 0; u < 16; ++u) g[u] = Hv[(size_t)c[u].x * 64 + lane];
#pragma unroll
            for (int u = 0; u < 16; ++u) {
                float wg = __uint_as_float(c[u].y);
                a0 += wg * bflo(g[u].x); a1 += wg * bfhi(g[u].x);
                a2 += wg * bflo(g[u].y); a3 += wg * bfhi(g[u].y);
            }
        }
        for (; e + 8 <= end; e += 8) {
#pragma unroll
            for (int u = 0; u < 8; ++u) c[u] = csr[e + u];
#pragma unroll
            for (int u = 0; u < 8; ++u) g[u] = Hv[(size_t)c[u].x * 64 + lane];
#pragma unroll
            for (int u = 0; u < 8; ++u) {
                float wg = __uint_as_float(c[u].y);
                a0 += wg * bflo(g[u].x); a1 += wg * bfhi(g[u].x);
                a2 += wg * bflo(g[u].y); a3 += wg * bfhi(g[u].y);
            }
        }
    }
    for (; e < end; ++e) {
        uint2 c = csr[e];
        uint2 g = Hv[(size_t)c.x * 64 + lane];
        float wgt = __uint_as_float(c.y);
        a0 += wgt * bflo(g.x); a1 += wgt * bfhi(g.x);
        a2 += wgt * bflo(g.y); a3 += wgt * bfhi(g.y);
    }
    float di = dis[i];
    float wsl = di * di;
    uint2 v = Hv[(size_t)i * 64 + lane];
    a0 += wsl * bflo(v.x); a1 += wsl * bfhi(v.x);
    a2 += wsl * bflo(v.y); a3 += wsl * bfhi(v.y);
    float4 bb = ((const float4*)b1)[lane];
    a0 = fmaxf(a0 + bb.x, 0.f); a1 = fmaxf(a1 + bb.y, 0.f);
    a2 = fmaxf(a2 + bb.z, 0.f); a3 = fmaxf(a3 + bb.w, 0.f);
    uint2 o;
    o.x = pack2(a0, a1);
    o.y = pack2(a2, a3);
    ((uint2*)outb)[(size_t)i * 64 + lane] = o;
}

// ---------------- GEMM2: H2(bf16 Mx40) = A(bf16 Mx256) * W2(256x40 fp32) ----------------

__global__ __launch_bounds__(256) void gemm2_k(const unsigned short* __restrict__ Ab,
                                               const float* __restrict__ W2,
                                               unsigned short* __restrict__ H2b, int M) {
    __shared__ float w2t[NCLASS][260];
    int t = threadIdx.x;
    for (int idx = t; idx < NHID * NCLASS; idx += 256) {
        int k = idx / NCLASS;
        int j = idx - k * NCLASS;
        w2t[j][k] = W2[idx];
    }
    __syncthreads();
    int i = blockIdx.x * 32 + (t >> 3);
    if (i >= M) return;
    int j0 = (t & 7) * 5;
    const uint2* arow = (const uint2*)(Ab + (size_t)i * NHID);
    float acc[5] = {0.f, 0.f, 0.f, 0.f, 0.f};
#pragma unroll 4
    for (int c = 0; c < 64; ++c) {
        uint2 v = arow[c];
        float a0 = bflo(v.x), a1 = bfhi(v.x), a2 = bflo(v.y), a3 = bfhi(v.y);
        int k = c * 4;
#pragma unroll
        for (int jj = 0; jj < 5; ++jj) {
            float4 q = *(const float4*)&w2t[j0 + jj][k];
            acc[jj] += a0 * q.x + a1 * q.y + a2 * q.z + a3 * q.w;
        }
    }
#pragma unroll
    for (int jj = 0; jj < 5; ++jj)
        H2b[(size_t)i * NCLASS + j0 + jj] = f2bf(acc[jj]);
}

// ---------------- agg2 + bias + fused log_softmax ----------------
// wave per node; lane = slot*10+jj (slot<6): 6 edges in flight per group,
// 2 groups per iter. Cross-slot reduce via shuffles; softmax on lanes 0..9.

__global__ __launch_bounds__(256) void agg2_k(const unsigned short* __restrict__ H2b,
                                              const int* __restrict__ offs,
                                              const uint2* __restrict__ csr,
                                              const float* __restrict__ dis,
                                              const float* __restrict__ b2,
                                              float* __restrict__ out, int n) {
    int lane = threadIdx.x & 63;
    int i = blockIdx.x * 4 + (threadIdx.x >> 6);
    if (i >= n) return;
    const uint2* Hv = (const uint2*)H2b;   // row = 10 uint2 (40 bf16)
    int slot = lane / 10;                  // 0..6
    int jj = lane - slot * 10;             // 0..9 (0..3 for lane>=60)
    bool act = (slot < 6);
    float a0 = 0.f, a1 = 0.f, a2 = 0.f, a3 = 0.f;
    int beg = offs[i], end = offs[i + 1];
    for (int e = beg; e < end; e += 12) {
        int idx0 = e + slot;
        int idx1 = e + 6 + slot;
        bool v0 = act && (idx0 < end);
        bool v1 = act && (idx1 < end);
        uint2 c0 = v0 ? csr[idx0] : make_uint2((unsigned)i, 0u);
        uint2 c1 = v1 ? csr[idx1] : make_uint2((unsigned)i, 0u);
        uint2 g0 = Hv[(size_t)c0.x * 10 + jj];
        uint2 g1 = Hv[(size_t)c1.x * 10 + jj];
        float w0 = __uint_as_float(c0.y);
        float w1 = __uint_as_float(c1.y);
        a0 += w0 * bflo(g0.x); a1 += w0 * bfhi(g0.x);
        a2 += w0 * bflo(g0.y); a3 += w0 * bfhi(g0.y);
        a0 += w1 * bflo(g1.x); a1 += w1 * bfhi(g1.x);
        a2 += w1 * bflo(g1.y); a3 += w1 * bfhi(g1.y);
    }
    // fold slots 3..5 into 0..2, then 1..2 into 0
    a0 += __shfl(a0, lane + 30, 64); a1 += __shfl(a1, lane + 30, 64);
    a2 += __shfl(a2, lane + 30, 64); a3 += __shfl(a3, lane + 30, 64);
    a0 = a0 + __shfl(a0, lane + 10, 64) + __shfl(a0, lane + 20, 64);
    a1 = a1 + __shfl(a1, lane + 10, 64) + __shfl(a1, lane + 20, 64);
    a2 = a2 + __shfl(a2, lane + 10, 64) + __shfl(a2, lane + 20, 64);
    a3 = a3 + __shfl(a3, lane + 10, 64) + __shfl(a3, lane + 20, 64);
    // lanes 0..9 now hold the full aggregate for feats [4*lane, 4*lane+4)
    bool act0 = (lane < 10);
    int jc = act0 ? lane : 0;
    float di = dis[i];
    float wsl = di * di;
    uint2 v = Hv[(size_t)i * 10 + jc];
    a0 += wsl * bflo(v.x); a1 += wsl * bfhi(v.x);
    a2 += wsl * bflo(v.y); a3 += wsl * bfhi(v.y);
    float4 bb = ((const float4*)b2)[jc];
    a0 += bb.x; a1 += bb.y; a2 += bb.z; a3 += bb.w;
    float m = act0 ? fmaxf(fmaxf(a0, a1), fmaxf(a2, a3)) : -INFINITY;
#pragma unroll
    for (int off = 8; off > 0; off >>= 1) m = fmaxf(m, __shfl_xor(m, off, 16));
    float s = act0 ? (expf(a0 - m) + expf(a1 - m) + expf(a2 - m) + expf(a3 - m)) : 0.f;
#pragma unroll
    for (int off = 8; off > 0; off >>= 1) s += __shfl_xor(s, off, 16);
    float ls = m + logf(s);
    if (act0) {
        float4 o = make_float4(a0 - ls, a1 - ls, a2 - ls, a3 - ls);
        ((float4*)(out + (size_t)i * NCLASS))[lane] = o;
    }
}

// ---------------- launch ----------------

extern "C" void kernel_launch(void* const* d_in, const int* in_sizes, int n_in,
                              void* d_out, int out_size, void* d_ws, size_t ws_size,
                              hipStream_t stream) {
    const float* x  = (const float*)d_in[0];
    const float* W1 = (const float*)d_in[1];
    const float* b1 = (const float*)d_in[2];
    const float* W2 = (const float*)d_in[3];
    const float* b2 = (const float*)d_in[4];
    const int*   ei = (const int*)d_in[5];   // int32-staged

    const int N = in_sizes[0] / NFEAT;      // 100000
    const int E = in_sizes[5] / 2;          // 3200000

    size_t off = 0;
    auto alloc = [&](size_t bytes) { size_t o = off; off += (bytes + 255) & ~(size_t)255; return o; };
    char* ws = (char*)d_ws;
    int*            cnt     = (int*)           (ws + alloc((size_t)N * 4));
    int*            offs    = (int*)           (ws + alloc((size_t)(N + 1) * 4));
    int*            cursor  = (int*)           (ws + alloc((size_t)N * 4));
    float*          dis     = (float*)         (ws + alloc((size_t)N * 4));
    int*            bsum    = (int*)           (ws + alloc(256 * 4));
    int*            boff    = (int*)           (ws + alloc(256 * 4));
    uint2*          csr     = (uint2*)         (ws + alloc((size_t)E * 8));
    unsigned short* wT      = (unsigned short*)(ws + alloc((size_t)NFEAT * NHID * 2));
    unsigned short* h1b     = (unsigned short*)(ws + alloc((size_t)N * NHID * 2));
    unsigned short* a1b     = (unsigned short*)(ws + alloc((size_t)N * NHID * 2));
    unsigned short* h2b     = (unsigned short*)(ws + alloc((size_t)N * NCLASS * 2));
    float*          out     = (float*)d_out;

    int nb_e = (E + 255) / 256;
    int nb_scan = (N + SCAN_CHUNK - 1) / SCAN_CHUNK;

    hipMemsetAsync(cnt, 0, (size_t)N * 4, stream);
    hist_k<<<nb_e, 256, 0, stream>>>(ei, cnt, E);
    scanA_k<<<nb_scan, 256, 0, stream>>>(cnt, bsum, dis, N);
    scanB_k<<<1, 256, 0, stream>>>(bsum, boff, nb_scan);
    scanC_k<<<nb_scan, 256, 0, stream>>>(cnt, boff, offs, cursor, N, E);
    fill_k<<<nb_e, 256, 0, stream>>>(ei, dis, cursor, csr, E);

    castw1_k<<<(NFEAT * NHID + 255) / 256, 256, 0, stream>>>(W1, wT);
    gemm1_k<<<(N + 63) / 64, 256, 0, stream>>>(x, wT, h1b, N);
    agg1_k<<<(N + 3) / 4, 256, 0, stream>>>(h1b, offs, csr, dis, b1, a1b, N);
    gemm2_k<<<(N + 31) / 32, 256, 0, stream>>>(a1b, W2, h2b, N);
    agg2_k<<<(N + 3) / 4, 256, 0, stream>>>(h2b, offs, csr, dis, b2, out, N);
}